// Round 5
// baseline (2033.928 us; speedup 1.0000x reference)
//
#include <hip/hip_runtime.h>
#include <hip/hip_bf16.h>
#include <cstdint>

// Problem constants
#define SS 512
#define OBS_N 32000
#define TT 1024
#define BB 64

// Main kernel: 16 waves (1024 threads). Waves w=(h,b) with b=w&7 (row-block),
// h=w>>3 (column half). Wave (b,h) processes rows [64b,64b+64) x cols
// {256h+64k+l : k<4}. Rows as f16 pairs: 24 pairs in VGPRs (96 u32/lane),
// 8 pairs in LDS (32 u32/lane). Columns for the scalar/epilogue phases are
// duplicated: waves b and b+8 both own alpha for cols 64b+l, which makes the
// P-vector each wave consumes wave-local (1 block barrier per step).
#define RPP 24
#define LPP 8
#define NW 16

typedef _Float16 h2 __attribute__((ext_vector_type(2)));

static __device__ __forceinline__ float wave_max(float v) {
#pragma unroll
  for (int m = 32; m >= 1; m >>= 1) v = fmaxf(v, __shfl_xor(v, m, 64));
  return v;
}
static __device__ __forceinline__ float wave_sum(float v) {
#pragma unroll
  for (int m = 32; m >= 1; m >>= 1) v += __shfl_xor(v, m, 64);
  return v;
}

// Fast full-wave max via DPP (result in lane 63, broadcast with readlane).
static __device__ __forceinline__ float wave_max_dpp(float x) {
  int v = __builtin_bit_cast(int, x);
#define DPP_STEP(ctrl)                                                        \
  {                                                                           \
    int t = __builtin_amdgcn_update_dpp(v, v, (ctrl), 0xf, 0xf, false);       \
    v = __builtin_bit_cast(                                                   \
        int, fmaxf(__builtin_bit_cast(float, v), __builtin_bit_cast(float, t)));\
  }
  DPP_STEP(0x111)  // row_shr:1
  DPP_STEP(0x112)  // row_shr:2
  DPP_STEP(0x114)  // row_shr:4
  DPP_STEP(0x118)  // row_shr:8
  DPP_STEP(0x142)  // row_bcast:15
  DPP_STEP(0x143)  // row_bcast:31
#undef DPP_STEP
  return __builtin_bit_cast(float, __builtin_amdgcn_readlane(v, 63));
}

static __device__ __forceinline__ float dot2f(h2 a, h2 b, float c) {
#if __has_builtin(__builtin_amdgcn_fdot2)
  return __builtin_amdgcn_fdot2(a, b, c, false);
#else
  return c + (float)a.x * (float)b.x + (float)a.y * (float)b.y;
#endif
}

static __device__ __forceinline__ h2 as_h2(uint32_t u) {
  return __builtin_bit_cast(h2, u);
}
static __device__ __forceinline__ uint32_t sel4(const uint4& v, int s) {
  return s == 0 ? v.x : s == 1 ? v.y : s == 2 ? v.z : v.w;
}

// ---------------- Prep 1: row logsumexp of observation_transitions [512 x 32000]
__global__ __launch_bounds__(256) void prep_obs_lse(const float* __restrict__ ot,
                                                    float* __restrict__ lse) {
  const int s = blockIdx.x;
  const int tid = threadIdx.x;
  const float4* row = (const float4*)(ot + (size_t)s * OBS_N);
  __shared__ float redm[4];
  __shared__ float reds[4];

  float m = -INFINITY;
  for (int k = tid; k < OBS_N / 4; k += 256) {
    float4 v = row[k];
    m = fmaxf(m, fmaxf(fmaxf(v.x, v.y), fmaxf(v.z, v.w)));
  }
  m = wave_max(m);
  if ((tid & 63) == 0) redm[tid >> 6] = m;
  __syncthreads();
  m = fmaxf(fmaxf(redm[0], redm[1]), fmaxf(redm[2], redm[3]));

  float ssum = 0.f;
  for (int k = tid; k < OBS_N / 4; k += 256) {
    float4 v = row[k];
    ssum += __expf(v.x - m) + __expf(v.y - m) + __expf(v.z - m) + __expf(v.w - m);
  }
  ssum = wave_sum(ssum);
  if ((tid & 63) == 0) reds[tid >> 6] = ssum;
  __syncthreads();
  if (tid == 0) {
    float s4 = reds[0] + reds[1] + reds[2] + reds[3];
    lse[s] = m + __logf(s4);
  }
}

// ---------------- Prep 1b: transpose obs table -> oT[o][j] (coalesced gather)
__global__ __launch_bounds__(256) void transpose_ot(const float* __restrict__ ot,
                                                    float* __restrict__ oT) {
  __shared__ float tile[32][33];
  const int o0 = blockIdx.x * 32;  // 1000 tiles along O (32000/32)
  const int j0 = blockIdx.y * 32;  // 16 tiles along S (512/32)
  const int tx = threadIdx.x & 31;
  const int ty = threadIdx.x >> 5;  // 0..7
#pragma unroll
  for (int r = 0; r < 32; r += 8)
    tile[ty + r][tx] = ot[(size_t)(j0 + ty + r) * OBS_N + (o0 + tx)];
  __syncthreads();
#pragma unroll
  for (int r = 0; r < 32; r += 8)
    oT[(size_t)(o0 + ty + r) * SS + (j0 + tx)] = tile[tx][ty + r];
}

// ---------------- Prep 2: E = softmax rows of state_transitions, f16, packed in
// pairs along i: EP[i2][j] = (f16 E[2*i2][j]) | (f16 E[2*i2+1][j] << 16)
__global__ __launch_bounds__(512) void prep_trans(const float* __restrict__ st,
                                                  uint32_t* __restrict__ EP) {
  const int r = blockIdx.x;  // handles rows 2r and 2r+1
  const int j = threadIdx.x;
  const int wv = j >> 6;
  float a0 = st[(size_t)(2 * r) * SS + j];
  float a1 = st[(size_t)(2 * r + 1) * SS + j];

  __shared__ float w0[8], w1[8], s0a[8], s1a[8];
  float m0 = wave_max(a0), m1 = wave_max(a1);
  if ((j & 63) == 0) { w0[wv] = m0; w1[wv] = m1; }
  __syncthreads();
  m0 = w0[0]; m1 = w1[0];
#pragma unroll
  for (int q = 1; q < 8; ++q) { m0 = fmaxf(m0, w0[q]); m1 = fmaxf(m1, w1[q]); }

  float e0 = __expf(a0 - m0), e1 = __expf(a1 - m1);
  float s0 = wave_sum(e0), s1 = wave_sum(e1);
  if ((j & 63) == 0) { s0a[wv] = s0; s1a[wv] = s1; }
  __syncthreads();
  s0 = 0.f; s1 = 0.f;
#pragma unroll
  for (int q = 0; q < 8; ++q) { s0 += s0a[q]; s1 += s1a[q]; }

  _Float16 h0 = (_Float16)(e0 / s0);
  _Float16 h1 = (_Float16)(e1 / s1);
  uint32_t u = ((uint32_t)__builtin_bit_cast(unsigned short, h1) << 16) |
               (uint32_t)__builtin_bit_cast(unsigned short, h0);
  EP[(size_t)r * SS + j] = u;
}

// ---------------- Prep 3: log_softmax of prior [512]
__global__ __launch_bounds__(512) void prep_prior(const float* __restrict__ pr,
                                                  float* __restrict__ lp) {
  const int j = threadIdx.x;
  const int wv = j >> 6;
  float a = pr[j];
  __shared__ float wm[8], ws[8];
  float m = wave_max(a);
  if ((j & 63) == 0) wm[wv] = m;
  __syncthreads();
  m = wm[0];
#pragma unroll
  for (int q = 1; q < 8; ++q) m = fmaxf(m, wm[q]);
  float e = __expf(a - m);
  float s = wave_sum(e);
  if ((j & 63) == 0) ws[wv] = s;
  __syncthreads();
  s = 0.f;
#pragma unroll
  for (int q = 0; q < 8; ++q) s += ws[q];
  lp[j] = a - m - __logf(s);
}

// ---------------- Main: one workgroup per chain, 16 waves, 1 barrier/step.
// __launch_bounds__(1024, 4): 4 waves/EU -> 1 block/CU, 128-VGPR budget which
// this layout fits WITHOUT spills (96 eR + ~25 working).
__global__ __launch_bounds__(1024, 4) void hmm_main(
    const uint32_t* __restrict__ EP, const float* __restrict__ lse_obs,
    const float* __restrict__ lp, const int* __restrict__ obs,
    const float* __restrict__ og, int sO, int sJ, float* __restrict__ out) {
  // eL[b][q][h][l][k] = EP[32b+24+q][256h+64k+l]; lane reads 16B contiguous.
  __shared__ __align__(16) uint32_t eL[8][LPP][2][64][4];   // 128 KiB
  __shared__ __align__(16) unsigned short ph16[NW][64];     // 2 KiB, wave-local
  __shared__ __align__(16) unsigned short ppb[2][8][SS];    // 16 KiB f16 partials
  __shared__ __align__(16) float wred[2][8];
  __shared__ float fin_m[8], fin_s[8];

  const int tid = threadIdx.x;
  const int w = tid >> 6;   // 0..15
  const int l = tid & 63;
  const int b = w & 7;      // row-block: rows [64b, 64b+64)
  const int h = w >> 3;     // column half for the dot phase
  const int bb = blockIdx.x;
  const int cP = 64 * b + l;  // epilogue column (duplicated across h)

  // Register-resident E: pairs [32b, 32b+24), cols 256h+64k+l (k<4)
  uint32_t eR[RPP * 4];
#pragma unroll
  for (int p = 0; p < RPP; ++p)
#pragma unroll
    for (int k = 0; k < 4; ++k)
      eR[p * 4 + k] = EP[(size_t)(32 * b + p) * SS + 256 * h + 64 * k + l];

  // Stage LDS tail pairs (each wave stages exactly its own slice)
#pragma unroll
  for (int q = 0; q < LPP; ++q) {
    const uint32_t* src = EP + (size_t)(32 * b + RPP + q) * SS + 256 * h + l;
    uint4 v;
    v.x = src[0];
    v.y = src[64];
    v.z = src[128];
    v.w = src[192];
    *(uint4*)&eL[b][q][h][l][0] = v;
  }

  const float lse_j = lse_obs[cP];
  const float lpj = lp[cP];
  const size_t jOff = (size_t)cP * sJ;
  const int* orow = obs + bb * TT;

  float alpha = og[(size_t)orow[0] * sO + jOff] - lse_j + lpj;
  float otv = og[(size_t)orow[1] * sO + jOff];  // prefetched for step 1

  __syncthreads();  // eL ready

  for (int t = 1; t <= TT; ++t) {
    const int par = t & 1;

    // Prefetch obs value for step t+1 (terminal obs id = 0 at t = TT)
    int o2 = (t <= TT - 2) ? orow[t + 1] : 0;
    float ot_pf = (t < TT) ? og[(size_t)o2 * sO + jOff] : 0.f;

    // Row-block max: this wave's 64 lanes hold alpha for rows [64b,64b+64)
    float mw = wave_max_dpp(alpha);
    if (l == 0 && h == 0) wred[par][b] = mw;

    // P = exp(alpha - mw) as f16; wave-local publish (dup waves write own copy)
    float Pj = __expf(alpha - mw);
    ph16[w][l] = __builtin_bit_cast(unsigned short, (_Float16)Pj);
    __builtin_amdgcn_wave_barrier();

    float acc[4] = {0.f, 0.f, 0.f, 0.f};
    const uint32_t* phu = (const uint32_t*)&ph16[w][0];  // pair p -> phu[p]

    // LDS tail first (issue b128 reads early): pairs 24..31
#pragma unroll
    for (int qg = 0; qg < 2; ++qg) {
      uint4 ph4 = *(const uint4*)&phu[RPP + 4 * qg];  // uniform -> broadcast
#pragma unroll
      for (int s = 0; s < 4; ++s) {
        const int q = 4 * qg + s;
        h2 phv = as_h2(sel4(ph4, s));
        const uint4 ev = *(const uint4*)&eL[b][q][h][l][0];
        acc[0] = dot2f(phv, as_h2(ev.x), acc[0]);
        acc[1] = dot2f(phv, as_h2(ev.y), acc[1]);
        acc[2] = dot2f(phv, as_h2(ev.z), acc[2]);
        acc[3] = dot2f(phv, as_h2(ev.w), acc[3]);
      }
    }

    // Register part: pairs 0..23
#pragma unroll
    for (int g = 0; g < 6; ++g) {
      uint4 ph4 = *(const uint4*)&phu[4 * g];
#pragma unroll
      for (int s = 0; s < 4; ++s) {
        const int p = 4 * g + s;
        h2 phv = as_h2(sel4(ph4, s));
#pragma unroll
        for (int k = 0; k < 4; ++k)
          acc[k] = dot2f(phv, as_h2(eR[p * 4 + k]), acc[k]);
      }
    }

    // Publish f16 partials for this wave's 4 dot-columns
#pragma unroll
    for (int k = 0; k < 4; ++k)
      ppb[par][b][256 * h + 64 * k + l] =
          __builtin_bit_cast(unsigned short, (_Float16)acc[k]);

    __syncthreads();  // the ONLY block barrier per step

    // Combine 8 row-block partials for column cP with exp-rescale
    const float4 wv0 = *(const float4*)&wred[par][0];
    const float4 wv1 = *(const float4*)&wred[par][4];
    float M = fmaxf(fmaxf(fmaxf(wv0.x, wv0.y), fmaxf(wv0.z, wv0.w)),
                    fmaxf(fmaxf(wv1.x, wv1.y), fmaxf(wv1.z, wv1.w)));
    float earg = wred[par][l & 7];
    float ee = __expf(earg - M);  // lane q<8 holds exp(m_q - M)

    float pred = 0.f;
#pragma unroll
    for (int q = 0; q < 8; ++q) {
      float eq = __builtin_bit_cast(
          float, __builtin_amdgcn_readlane(__builtin_bit_cast(int, ee), q));
      float pq = (float)__builtin_bit_cast(_Float16, ppb[par][q][cP]);
      pred = fmaf(eq, pq, pred);
    }
    alpha = M + __logf(pred) + (otv - lse_j);
    otv = ot_pf;
  }

  // Final logsumexp over states (h==0 waves cover all 512 columns once)
  float m = wave_max(alpha);
  if (l == 0 && h == 0) fin_m[b] = m;
  __syncthreads();
  float M = fin_m[0];
#pragma unroll
  for (int q = 1; q < 8; ++q) M = fmaxf(M, fin_m[q]);
  float e = __expf(alpha - M);
  float s = wave_sum(e);
  if (l == 0 && h == 0) fin_s[b] = s;
  __syncthreads();
  if (tid == 0) {
    float tot = 0.f;
#pragma unroll
    for (int q = 0; q < 8; ++q) tot += fin_s[q];
    out[bb] = M + __logf(tot);
  }
}

extern "C" void kernel_launch(void* const* d_in, const int* in_sizes, int n_in,
                              void* d_out, int out_size, void* d_ws, size_t ws_size,
                              hipStream_t stream) {
  const int* obs = (const int*)d_in[0];        // [64, 1024] int32
  const float* st = (const float*)d_in[1];     // [512, 512] f32
  const float* ot = (const float*)d_in[2];     // [512, 32000] f32
  const float* pr = (const float*)d_in[3];     // [512] f32
  float* out = (float*)d_out;                  // [64] f32

  char* ws = (char*)d_ws;
  uint32_t* EP = (uint32_t*)ws;                     // 512 KiB
  float* lse_obs = (float*)(ws + 524288);           // 2 KiB
  float* lprior = (float*)(ws + 526336);            // 2 KiB
  float* oT = (float*)(ws + 528384);                // 65.5 MiB (optional)
  const size_t need = 528384 + (size_t)OBS_N * SS * sizeof(float);

  prep_obs_lse<<<SS, 256, 0, stream>>>(ot, lse_obs);
  prep_trans<<<SS / 2, SS, 0, stream>>>(st, EP);
  prep_prior<<<1, SS, 0, stream>>>(pr, lprior);

  const float* og = ot;
  int sO = 1, sJ = OBS_N;
  if (ws_size >= need) {
    transpose_ot<<<dim3(OBS_N / 32, SS / 32), 256, 0, stream>>>(ot, oT);
    og = oT; sO = SS; sJ = 1;
  }
  hmm_main<<<BB, 1024, 0, stream>>>(EP, lse_obs, lprior, obs, og, sO, sJ, out);
}

// Round 7
// 1793.474 us; speedup vs baseline: 1.1341x; 1.1341x over previous
//
#include <hip/hip_runtime.h>
#include <hip/hip_bf16.h>
#include <cstdint>

// Problem constants
#define SS 512
#define OBS_N 32000
#define TT 1024
#define BB 64

// 8 waves of 64 lanes. Wave w owns rows [64w,64w+64) = f16-pair rows
// [32w,32w+32): 24 pairs in explicit SSA register vectors (rule #20: named
// ext_vector variables, literal indices only -> cannot be demoted to
// scratch), 8 pairs in LDS.
#define RPW 24

typedef _Float16 h2 __attribute__((ext_vector_type(2)));
typedef unsigned int u32x8 __attribute__((ext_vector_type(8)));

static __device__ __forceinline__ float wave_max(float v) {
#pragma unroll
  for (int m = 32; m >= 1; m >>= 1) v = fmaxf(v, __shfl_xor(v, m, 64));
  return v;
}
static __device__ __forceinline__ float wave_sum(float v) {
#pragma unroll
  for (int m = 32; m >= 1; m >>= 1) v += __shfl_xor(v, m, 64);
  return v;
}

// Fast full-wave max via DPP (result in lane 63, broadcast with readlane).
static __device__ __forceinline__ float wave_max_dpp(float x) {
  int v = __builtin_bit_cast(int, x);
#define DPP_STEP(ctrl)                                                        \
  {                                                                           \
    int t = __builtin_amdgcn_update_dpp(v, v, (ctrl), 0xf, 0xf, false);       \
    v = __builtin_bit_cast(                                                   \
        int, fmaxf(__builtin_bit_cast(float, v), __builtin_bit_cast(float, t)));\
  }
  DPP_STEP(0x111)  // row_shr:1
  DPP_STEP(0x112)  // row_shr:2
  DPP_STEP(0x114)  // row_shr:4
  DPP_STEP(0x118)  // row_shr:8
  DPP_STEP(0x142)  // row_bcast:15
  DPP_STEP(0x143)  // row_bcast:31
#undef DPP_STEP
  return __builtin_bit_cast(float, __builtin_amdgcn_readlane(v, 63));
}

static __device__ __forceinline__ float dot2f(h2 a, h2 b, float c) {
#if __has_builtin(__builtin_amdgcn_fdot2)
  return __builtin_amdgcn_fdot2(a, b, c, false);
#else
  return c + (float)a.x * (float)b.x + (float)a.y * (float)b.y;
#endif
}

static __device__ __forceinline__ h2 as_h2(uint32_t u) {
  return __builtin_bit_cast(h2, u);
}
static __device__ __forceinline__ uint32_t sel4(const uint4& v, int s) {
  return s == 0 ? v.x : s == 1 ? v.y : s == 2 ? v.z : v.w;
}

// ---------------- Prep 1: row logsumexp of observation_transitions [512 x 32000]
__global__ __launch_bounds__(256) void prep_obs_lse(const float* __restrict__ ot,
                                                    float* __restrict__ lse) {
  const int s = blockIdx.x;
  const int tid = threadIdx.x;
  const float4* row = (const float4*)(ot + (size_t)s * OBS_N);
  __shared__ float redm[4];
  __shared__ float reds[4];

  float m = -INFINITY;
  for (int k = tid; k < OBS_N / 4; k += 256) {
    float4 v = row[k];
    m = fmaxf(m, fmaxf(fmaxf(v.x, v.y), fmaxf(v.z, v.w)));
  }
  m = wave_max(m);
  if ((tid & 63) == 0) redm[tid >> 6] = m;
  __syncthreads();
  m = fmaxf(fmaxf(redm[0], redm[1]), fmaxf(redm[2], redm[3]));

  float ssum = 0.f;
  for (int k = tid; k < OBS_N / 4; k += 256) {
    float4 v = row[k];
    ssum += __expf(v.x - m) + __expf(v.y - m) + __expf(v.z - m) + __expf(v.w - m);
  }
  ssum = wave_sum(ssum);
  if ((tid & 63) == 0) reds[tid >> 6] = ssum;
  __syncthreads();
  if (tid == 0) {
    float s4 = reds[0] + reds[1] + reds[2] + reds[3];
    lse[s] = m + __logf(s4);
  }
}

// ---------------- Prep 1b: transpose obs table -> oT[o][j] (coalesced gather)
__global__ __launch_bounds__(256) void transpose_ot(const float* __restrict__ ot,
                                                    float* __restrict__ oT) {
  __shared__ float tile[32][33];
  const int o0 = blockIdx.x * 32;
  const int j0 = blockIdx.y * 32;
  const int tx = threadIdx.x & 31;
  const int ty = threadIdx.x >> 5;  // 0..7
#pragma unroll
  for (int r = 0; r < 32; r += 8)
    tile[ty + r][tx] = ot[(size_t)(j0 + ty + r) * OBS_N + (o0 + tx)];
  __syncthreads();
#pragma unroll
  for (int r = 0; r < 32; r += 8)
    oT[(size_t)(o0 + ty + r) * SS + (j0 + tx)] = tile[tx][ty + r];
}

// ---------------- Prep 2: E = softmax rows of state_transitions, f16, packed in
// pairs along i: EP[i2][j] = (f16 E[2*i2][j]) | (f16 E[2*i2+1][j] << 16)
__global__ __launch_bounds__(512) void prep_trans(const float* __restrict__ st,
                                                  uint32_t* __restrict__ EP) {
  const int r = blockIdx.x;
  const int j = threadIdx.x;
  const int wv = j >> 6;
  float a0 = st[(size_t)(2 * r) * SS + j];
  float a1 = st[(size_t)(2 * r + 1) * SS + j];

  __shared__ float w0[8], w1[8], s0a[8], s1a[8];
  float m0 = wave_max(a0), m1 = wave_max(a1);
  if ((j & 63) == 0) { w0[wv] = m0; w1[wv] = m1; }
  __syncthreads();
  m0 = w0[0]; m1 = w1[0];
#pragma unroll
  for (int q = 1; q < 8; ++q) { m0 = fmaxf(m0, w0[q]); m1 = fmaxf(m1, w1[q]); }

  float e0 = __expf(a0 - m0), e1 = __expf(a1 - m1);
  float s0 = wave_sum(e0), s1 = wave_sum(e1);
  if ((j & 63) == 0) { s0a[wv] = s0; s1a[wv] = s1; }
  __syncthreads();
  s0 = 0.f; s1 = 0.f;
#pragma unroll
  for (int q = 0; q < 8; ++q) { s0 += s0a[q]; s1 += s1a[q]; }

  _Float16 h0 = (_Float16)(e0 / s0);
  _Float16 h1 = (_Float16)(e1 / s1);
  uint32_t u = ((uint32_t)__builtin_bit_cast(unsigned short, h1) << 16) |
               (uint32_t)__builtin_bit_cast(unsigned short, h0);
  EP[(size_t)r * SS + j] = u;
}

// ---------------- Prep 3: log_softmax of prior [512]
__global__ __launch_bounds__(512) void prep_prior(const float* __restrict__ pr,
                                                  float* __restrict__ lp) {
  const int j = threadIdx.x;
  const int wv = j >> 6;
  float a = pr[j];
  __shared__ float wm[8], ws[8];
  float m = wave_max(a);
  if ((j & 63) == 0) wm[wv] = m;
  __syncthreads();
  m = wm[0];
#pragma unroll
  for (int q = 1; q < 8; ++q) m = fmaxf(m, wm[q]);
  float e = __expf(a - m);
  float s = wave_sum(e);
  if ((j & 63) == 0) ws[wv] = s;
  __syncthreads();
  s = 0.f;
#pragma unroll
  for (int q = 0; q < 8; ++q) s += ws[q];
  lp[j] = a - m - __logf(s);
}

// ---------------- Main: one workgroup per chain, 8 waves, 1 barrier/step.
__attribute__((amdgpu_waves_per_eu(2, 2))) __global__ void
__launch_bounds__(512) hmm_main(
    const uint32_t* __restrict__ EP, const float* __restrict__ lse_obs,
    const float* __restrict__ lp, const int* __restrict__ obs,
    const float* __restrict__ og, int sO, int sJ, float* __restrict__ out) {
  // Tail E pairs, lane-contiguous 16B chunks: eL[tq][c][l][m] holds
  // EP[pairrow(tq)][(c*4+m)*64 + l] -> wave64 ds_read_b128 is contiguous 1KiB.
  __shared__ uint32_t eL[64][2][64][4];                    // 128 KiB
  __shared__ __align__(16) unsigned short ph16[8][64];     // 1 KiB, wave-local
  __shared__ __align__(16) unsigned short ppb[2][8][SS];   // 16 KiB f16 partials
  __shared__ __align__(16) float wred[2][8];
  __shared__ float fin_m[8], fin_s[8];

  const int tid = threadIdx.x;
  const int w = tid >> 6;
  const int l = tid & 63;
  const int b = blockIdx.x;
  const int j = tid;  // column ownership for scalar phases

  // Register-resident E: wave w pairs [32w, 32w+24), lane l cols {l+64k}.
  // 24 NAMED ext_vector SSA values -> must live in registers (no scratch).
#define LOADER(P)                                                          \
  u32x8 eR##P;                                                             \
  {                                                                        \
    const uint32_t* src = EP + (size_t)(32 * w + (P)) * SS + l;            \
    eR##P = (u32x8){src[0],   src[64],  src[128], src[192],                \
                    src[256], src[320], src[384], src[448]};               \
  }
  LOADER(0)  LOADER(1)  LOADER(2)  LOADER(3)  LOADER(4)  LOADER(5)
  LOADER(6)  LOADER(7)  LOADER(8)  LOADER(9)  LOADER(10) LOADER(11)
  LOADER(12) LOADER(13) LOADER(14) LOADER(15) LOADER(16) LOADER(17)
  LOADER(18) LOADER(19) LOADER(20) LOADER(21) LOADER(22) LOADER(23)
#undef LOADER

  // Stage LDS tail pairs: tq = 8*w' + q -> pair row 32*w' + 24 + q
  for (int idx = tid; idx < 64 * 2 * 64; idx += 512) {
    int tq = idx >> 7;
    int c = (idx >> 6) & 1;
    int ll = idx & 63;
    int prow = 32 * (tq >> 3) + RPW + (tq & 7);
    const uint32_t* src = EP + (size_t)prow * SS + c * 256 + ll;
    eL[tq][c][ll][0] = src[0];
    eL[tq][c][ll][1] = src[64];
    eL[tq][c][ll][2] = src[128];
    eL[tq][c][ll][3] = src[192];
  }

  const float lse_j = lse_obs[j];
  const float lpj = lp[j];
  const size_t jOff = (size_t)j * sJ;
  const int* orow = obs + b * TT;

  float alpha = og[(size_t)orow[0] * sO + jOff] - lse_j + lpj;
  float otv = og[(size_t)orow[1] * sO + jOff];  // prefetched for step 1

  __syncthreads();  // eL ready

  for (int t = 1; t <= TT; ++t) {
    const int par = t & 1;

    // Prefetch obs value for step t+1 (terminal obs id = 0 at t = TT)
    int o2 = (t <= TT - 2) ? orow[t + 1] : 0;
    float ot_pf = (t < TT) ? og[(size_t)o2 * sO + jOff] : 0.f;

    // Per-wave max (no cross-wave barrier; rescaled after the dot)
    float mw = wave_max_dpp(alpha);
    if (l == 0) wred[par][w] = mw;

    // P = exp(alpha - mw) as f16, wave-local through LDS (wave is lockstep)
    float Pj = __expf(alpha - mw);
    ph16[w][l] = __builtin_bit_cast(unsigned short, (_Float16)Pj);
    __builtin_amdgcn_wave_barrier();

    float a0 = 0.f, a1 = 0.f, a2 = 0.f, a3 = 0.f;
    float a4 = 0.f, a5 = 0.f, a6 = 0.f, a7 = 0.f;
    const uint32_t* phu = (const uint32_t*)&ph16[w][0];  // pair p -> phu[p]

    // LDS tail first (issue b128 reads early): pairs 24..31 of this wave
#define DOT_L(Q, PH)                                                       \
  {                                                                        \
    h2 phv = as_h2(PH);                                                    \
    const uint4 c0 = *(const uint4*)&eL[w * 8 + (Q)][0][l][0];             \
    const uint4 c1 = *(const uint4*)&eL[w * 8 + (Q)][1][l][0];             \
    a0 = dot2f(phv, as_h2(c0.x), a0); a1 = dot2f(phv, as_h2(c0.y), a1);    \
    a2 = dot2f(phv, as_h2(c0.z), a2); a3 = dot2f(phv, as_h2(c0.w), a3);    \
    a4 = dot2f(phv, as_h2(c1.x), a4); a5 = dot2f(phv, as_h2(c1.y), a5);    \
    a6 = dot2f(phv, as_h2(c1.z), a6); a7 = dot2f(phv, as_h2(c1.w), a7);    \
  }
    {
      uint4 ph4 = *(const uint4*)&phu[24];
      DOT_L(0, sel4(ph4, 0)) DOT_L(1, sel4(ph4, 1))
      DOT_L(2, sel4(ph4, 2)) DOT_L(3, sel4(ph4, 3))
    }
    {
      uint4 ph4 = *(const uint4*)&phu[28];
      DOT_L(4, sel4(ph4, 0)) DOT_L(5, sel4(ph4, 1))
      DOT_L(6, sel4(ph4, 2)) DOT_L(7, sel4(ph4, 3))
    }
#undef DOT_L

    // Register part: pairs 0..23, literal vector-element indices only
#define DOT_R1(P, PH)                                                      \
  {                                                                        \
    h2 phv = as_h2(PH);                                                    \
    a0 = dot2f(phv, as_h2(eR##P[0]), a0);                                  \
    a1 = dot2f(phv, as_h2(eR##P[1]), a1);                                  \
    a2 = dot2f(phv, as_h2(eR##P[2]), a2);                                  \
    a3 = dot2f(phv, as_h2(eR##P[3]), a3);                                  \
    a4 = dot2f(phv, as_h2(eR##P[4]), a4);                                  \
    a5 = dot2f(phv, as_h2(eR##P[5]), a5);                                  \
    a6 = dot2f(phv, as_h2(eR##P[6]), a6);                                  \
    a7 = dot2f(phv, as_h2(eR##P[7]), a7);                                  \
  }
#define DOT_R4(G, P0, P1, P2, P3)                                          \
  {                                                                        \
    uint4 ph4 = *(const uint4*)&phu[4 * (G)];                              \
    DOT_R1(P0, sel4(ph4, 0)) DOT_R1(P1, sel4(ph4, 1))                      \
    DOT_R1(P2, sel4(ph4, 2)) DOT_R1(P3, sel4(ph4, 3))                      \
  }
    DOT_R4(0, 0, 1, 2, 3)
    DOT_R4(1, 4, 5, 6, 7)
    DOT_R4(2, 8, 9, 10, 11)
    DOT_R4(3, 12, 13, 14, 15)
    DOT_R4(4, 16, 17, 18, 19)
    DOT_R4(5, 20, 21, 22, 23)
#undef DOT_R4
#undef DOT_R1

    // Publish f16 partials
    ppb[par][w][0 * 64 + l] = __builtin_bit_cast(unsigned short, (_Float16)a0);
    ppb[par][w][1 * 64 + l] = __builtin_bit_cast(unsigned short, (_Float16)a1);
    ppb[par][w][2 * 64 + l] = __builtin_bit_cast(unsigned short, (_Float16)a2);
    ppb[par][w][3 * 64 + l] = __builtin_bit_cast(unsigned short, (_Float16)a3);
    ppb[par][w][4 * 64 + l] = __builtin_bit_cast(unsigned short, (_Float16)a4);
    ppb[par][w][5 * 64 + l] = __builtin_bit_cast(unsigned short, (_Float16)a5);
    ppb[par][w][6 * 64 + l] = __builtin_bit_cast(unsigned short, (_Float16)a6);
    ppb[par][w][7 * 64 + l] = __builtin_bit_cast(unsigned short, (_Float16)a7);

    __syncthreads();  // the ONLY barrier per step

    // Global max + rescaled combine
    const float4 wv0 = *(const float4*)&wred[par][0];
    const float4 wv1 = *(const float4*)&wred[par][4];
    float M = fmaxf(fmaxf(fmaxf(wv0.x, wv0.y), fmaxf(wv0.z, wv0.w)),
                    fmaxf(fmaxf(wv1.x, wv1.y), fmaxf(wv1.z, wv1.w)));
    float earg = wred[par][l & 7];
    float ee = __expf(earg - M);  // lane q<8 holds exp(m_q - M)

    float pred = 0.f;
#pragma unroll
    for (int q = 0; q < 8; ++q) {
      float eq = __builtin_bit_cast(
          float, __builtin_amdgcn_readlane(__builtin_bit_cast(int, ee), q));
      float pq = (float)__builtin_bit_cast(_Float16, ppb[par][q][j]);
      pred = fmaf(eq, pq, pred);
    }
    alpha = M + __logf(pred) + (otv - lse_j);
    otv = ot_pf;
  }

  // Final logsumexp over states
  float m = wave_max(alpha);
  if (l == 0) fin_m[w] = m;
  __syncthreads();
  float M = fin_m[0];
#pragma unroll
  for (int q = 1; q < 8; ++q) M = fmaxf(M, fin_m[q]);
  float e = __expf(alpha - M);
  float s = wave_sum(e);
  if (l == 0) fin_s[w] = s;
  __syncthreads();
  if (tid == 0) {
    float tot = 0.f;
#pragma unroll
    for (int q = 0; q < 8; ++q) tot += fin_s[q];
    out[b] = M + __logf(tot);
  }
}

extern "C" void kernel_launch(void* const* d_in, const int* in_sizes, int n_in,
                              void* d_out, int out_size, void* d_ws, size_t ws_size,
                              hipStream_t stream) {
  const int* obs = (const int*)d_in[0];        // [64, 1024] int32
  const float* st = (const float*)d_in[1];     // [512, 512] f32
  const float* ot = (const float*)d_in[2];     // [512, 32000] f32
  const float* pr = (const float*)d_in[3];     // [512] f32
  float* out = (float*)d_out;                  // [64] f32

  char* ws = (char*)d_ws;
  uint32_t* EP = (uint32_t*)ws;                     // 512 KiB
  float* lse_obs = (float*)(ws + 524288);           // 2 KiB
  float* lprior = (float*)(ws + 526336);            // 2 KiB
  float* oT = (float*)(ws + 528384);                // 65.5 MiB (optional)
  const size_t need = 528384 + (size_t)OBS_N * SS * sizeof(float);

  prep_obs_lse<<<SS, 256, 0, stream>>>(ot, lse_obs);
  prep_trans<<<SS / 2, SS, 0, stream>>>(st, EP);
  prep_prior<<<1, SS, 0, stream>>>(pr, lprior);

  const float* og = ot;
  int sO = 1, sJ = OBS_N;
  if (ws_size >= need) {
    transpose_ot<<<dim3(OBS_N / 32, SS / 32), 256, 0, stream>>>(ot, oT);
    og = oT; sO = SS; sJ = 1;
  }
  hmm_main<<<BB, SS, 0, stream>>>(EP, lse_obs, lprior, obs, og, sO, sJ, out);
}